// Round 2
// baseline (604.804 us; speedup 1.0000x reference)
//
#include <hip/hip_runtime.h>

#define SEQ 128
#define HID 32
#define TPB 128   // 2 waves, 16 nodes per block
#define XS 56     // LDS row stride in shorts: 112B = 7*16B -> conflict-free b128 pattern

typedef __attribute__((ext_vector_type(8))) short short8;   // 8 bf16 = 4 VGPR
typedef __attribute__((ext_vector_type(4))) short short4v;  // 4 shorts = 8B
typedef __attribute__((ext_vector_type(4))) float floatx4;  // MFMA acc

// ---------------- GCN prep ----------------

__global__ void count_kernel(const int* __restrict__ idx, int E, int* __restrict__ cnt) {
    int e = (blockIdx.x * blockDim.x + threadIdx.x) * 4;
    if (((E & 3) == 0) && e + 3 < E) {
        int4 d = *(const int4*)(idx + E + e);   // 16B aligned: E%4==0, e%4==0
        atomicAdd(&cnt[d.x], 1);
        atomicAdd(&cnt[d.y], 1);
        atomicAdd(&cnt[d.z], 1);
        atomicAdd(&cnt[d.w], 1);
    } else {
        int lim = min(e + 4, E);
        for (int k = e; k < lim; ++k) atomicAdd(&cnt[idx[E + k]], 1);
    }
}

// dinv = rsqrt(deg+1); also pre-scale xs[i] = x[i]*dinv[i] so scatter gathers ONE
// 8B stream per edge instead of two independent random lines (x2 + dinv).
__global__ void dinv_xs_kernel(float* __restrict__ buf, const float2* __restrict__ x2,
                               float2* __restrict__ xs2, int n) {
    int i = blockIdx.x * blockDim.x + threadIdx.x;
    if (i < n) {
        float dv = rsqrtf((float)__float_as_int(buf[i]) + 1.0f);
        buf[i] = dv;
        float2 xx = x2[i];
        xs2[i] = make_float2(xx.x * dv, xx.y * dv);
    }
}

__global__ void dinv_kernel(float* __restrict__ buf, int n) {  // fallback (small ws)
    int i = blockIdx.x * blockDim.x + threadIdx.x;
    if (i < n) buf[i] = rsqrtf((float)__float_as_int(buf[i]) + 1.0f);
}

// agg2[dst] += xs[src]   (xs pre-scaled by dinv[src]; dinv[dst] applied at staging)
// unsafeAtomicAdd -> native no-return global_atomic_add_f32 (never a CAS loop).
__global__ void scatter_xs_kernel(const int* __restrict__ idx, int E,
                                  const float2* __restrict__ xs2,
                                  float* __restrict__ agg2) {
    int e = (blockIdx.x * blockDim.x + threadIdx.x) * 4;
    if (((E & 3) == 0) && e + 3 < E) {
        int4 s = *(const int4*)(idx + e);
        int4 d = *(const int4*)(idx + E + e);
        float2 v0 = xs2[s.x];
        float2 v1 = xs2[s.y];
        float2 v2 = xs2[s.z];
        float2 v3 = xs2[s.w];
        unsafeAtomicAdd(&agg2[2 * d.x + 0], v0.x);
        unsafeAtomicAdd(&agg2[2 * d.x + 1], v0.y);
        unsafeAtomicAdd(&agg2[2 * d.y + 0], v1.x);
        unsafeAtomicAdd(&agg2[2 * d.y + 1], v1.y);
        unsafeAtomicAdd(&agg2[2 * d.z + 0], v2.x);
        unsafeAtomicAdd(&agg2[2 * d.z + 1], v2.y);
        unsafeAtomicAdd(&agg2[2 * d.w + 0], v3.x);
        unsafeAtomicAdd(&agg2[2 * d.w + 1], v3.y);
    } else {
        int lim = min(e + 4, E);
        for (int k = e; k < lim; ++k) {
            int s = idx[k];
            int d = idx[E + k];
            float2 v = xs2[s];
            unsafeAtomicAdd(&agg2[2 * d + 0], v.x);
            unsafeAtomicAdd(&agg2[2 * d + 1], v.y);
        }
    }
}

// fallback scatter (workspace too small for xs plane): gather x2 + dinv per edge
__global__ void scatter_kernel(const int* __restrict__ idx, int E,
                               const float2* __restrict__ x2,
                               const float* __restrict__ dinv,
                               float* __restrict__ agg2) {
    int e = blockIdx.x * blockDim.x + threadIdx.x;
    if (e < E) {
        int s = idx[e];
        int d = idx[E + e];
        float ns = dinv[s];
        float2 xs = x2[s];
        unsafeAtomicAdd(&agg2[2 * d + 0], xs.x * ns);
        unsafeAtomicAdd(&agg2[2 * d + 1], xs.y * ns);
    }
}

// ---------------- MFMA LSTM, 2 waves / 16 nodes, low-glue ----------------
// Wave w owns gates i,f,g,o for units 8q+4w+r (row-permuted W tiles; layout
// HW-verified rounds 5/6). h and xg cross the wave boundary through LDS rows
// of SEPARATED hi/lo shorts (32 units x 2B, stride 112B = 7*16B): one
// ds_read_b128 at [l15*112 + 16q] IS the lane's short8 B-frag -> zero unpack
// VALU, and 28*l15 mod 32 has period 8 -> only free 2-way bank aliasing
// (96B stride was period-4 -> 4-way conflicts, 1.5e7/dispatch).
// Single barrier per step: epoch reads buf p (xg(t), h(t-1)), writes buf p^1
// (xg(t+1), h(t)) -- double-buffer makes one __syncthreads race-free.

__device__ __forceinline__ float sigm_f(float x) {
    return __builtin_amdgcn_rcpf(1.0f + __expf(-x));
}
__device__ __forceinline__ float tanh_f(float x) {
    return fmaf(__builtin_amdgcn_rcpf(1.0f + __expf(-2.0f * x)), 2.0f, -1.0f);
}
// truncation split: f = hi + lo (~2^-16 rel); 3-term MFMA keeps fp32-like precision
__device__ __forceinline__ void fsplit(float f, short& hi, short& lo) {
    unsigned u = __float_as_uint(f);
    hi = (short)(u >> 16);
    float r = f - __uint_as_float(u & 0xFFFF0000u);
    lo = (short)(__float_as_uint(r) >> 16);
}

__global__ __launch_bounds__(TPB, 2) void lstm_mfma3_kernel(
    const float2* __restrict__ x2, const float* __restrict__ dinv,
    const float2* __restrict__ agg2, int N,
    const float* __restrict__ gcn_W, const float* __restrict__ gcn_b,
    const float* __restrict__ w_ih, const float* __restrict__ w_hh,
    const float* __restrict__ b_ih, const float* __restrict__ b_hh,
    const float* __restrict__ fc_W, const float* __restrict__ fc_b,
    float* __restrict__ out) {
    __shared__ float2 ubuf[16][SEQ + 1];                 // 16.5 KB (col 128 = scratch)
    __shared__ __align__(16) short xgh[2][16][XS];       // xg hi, row=32 units + pad
    __shared__ __align__(16) short xgl[2][16][XS];       // xg lo
    __shared__ __align__(16) short hhb[2][16][XS];       // h hi
    __shared__ __align__(16) short hlb[2][16][XS];       // h lo
    __shared__ float fcp[2][16];

    const int tid = threadIdx.x;
    const int w = tid >> 6;       // wave id = mtl
    const int lane = tid & 63;
    const int l15 = lane & 15;
    const int q = lane >> 4;
    const int base = blockIdx.x * 16;

    // ---- Phase A: stage u[node][t] = dv*(agg + x*dv) into LDS (coalesced) ----
    {
        const float2* agb = agg2 + (size_t)base * SEQ;
        const float2* xb  = x2   + (size_t)base * SEQ;
        const float*  db  = dinv + (size_t)base * SEQ;
        const int lim = min(16 * SEQ, (N - base) * SEQ);
        for (int i = tid; i < 16 * SEQ; i += TPB) {
            float2 v = make_float2(0.f, 0.f);
            if (i < lim) {
                float dv = db[i];
                float2 a = agb[i];
                float2 xx = xb[i];
                v = make_float2(dv * fmaf(xx.x, dv, a.x), dv * fmaf(xx.y, dv, a.y));
            }
            ubuf[i >> 7][i & 127] = v;
        }
    }

    // ---- constant A-frags (4 tiles = gates i,f,g,o at mtl=w), hi/lo bf16 ----
    short8 AiH[4], AiL[4], AhH[4], AhL[4];
    floatx4 biasC[4];
    #pragma unroll
    for (int g = 0; g < 4; ++g) {
        const int arow = g * 32 + 8 * (l15 >> 2) + 4 * w + (l15 & 3);
        const float* wi = w_ih + arow * HID + 8 * q;
        const float* wh = w_hh + arow * HID + 8 * q;
        #pragma unroll
        for (int j = 0; j < 8; ++j) {
            short h16, l16;
            fsplit(wi[j], h16, l16); AiH[g][j] = h16; AiL[g][j] = l16;
            fsplit(wh[j], h16, l16); AhH[g][j] = h16; AhL[g][j] = l16;
        }
        #pragma unroll
        for (int r = 0; r < 4; ++r) {
            const int brow = g * 32 + 8 * q + 4 * w + r;
            biasC[g][r] = b_ih[brow] + b_hh[brow];
        }
    }

    // ---- GCN consts for xg units owned by THIS lane: u = 16w + 4q + r ----
    float wg0[4], wg1[4], gbc[4], fcw[4];
    #pragma unroll
    for (int r = 0; r < 4; ++r) {
        const int u = 16 * w + 4 * q + r;
        wg0[r] = gcn_W[u];
        wg1[r] = gcn_W[HID + u];
        gbc[r] = gcn_b[u];
        fcw[r] = fc_W[8 * q + 4 * w + r];   // FC consts for own C-slots
    }

    float c[4] = {0.f, 0.f, 0.f, 0.f};
    float ho[4] = {0.f, 0.f, 0.f, 0.f};

    __syncthreads();  // ubuf staged

    // ---- prologue: xg(0) and h(-1)=0 into buffer 0 ----
    {
        float2 uu = ubuf[l15][0];
        short hi[4], lo[4];
        #pragma unroll
        for (int r = 0; r < 4; ++r) {
            float g = fmaxf(fmaf(uu.x, wg0[r], fmaf(uu.y, wg1[r], gbc[r])), 0.f);
            fsplit(g, hi[r], lo[r]);
        }
        *(short4v*)&xgh[0][l15][16 * w + 4 * q] = (short4v){hi[0], hi[1], hi[2], hi[3]};
        *(short4v*)&xgl[0][l15][16 * w + 4 * q] = (short4v){lo[0], lo[1], lo[2], lo[3]};
        *(short4v*)&hhb[0][l15][8 * q + 4 * w] = (short4v){0, 0, 0, 0};
        *(short4v*)&hlb[0][l15][8 * q + 4 * w] = (short4v){0, 0, 0, 0};
    }
    __syncthreads();

    int p = 0;
    #pragma unroll 1
    for (int t = 0; t < SEQ; ++t) {
        // B-frags direct from LDS: element j == unit 8q+j  (zero unpack)
        const short8 xh = *(const short8*)&xgh[p][l15][8 * q];
        const short8 xl = *(const short8*)&xgl[p][l15][8 * q];
        const short8 hh = *(const short8*)&hhb[p][l15][8 * q];
        const short8 hl = *(const short8*)&hlb[p][l15][8 * q];

        // 8 independent MFMA chains of depth 3 (x-terms in accA, h-terms in accB)
        // instead of 4 chains of depth 6: halves dependent-MFMA latency per step.
        floatx4 accA[4], accB[4];
        #pragma unroll
        for (int g = 0; g < 4; ++g) {
            accA[g] = biasC[g];
            accB[g] = (floatx4){0.f, 0.f, 0.f, 0.f};
        }
        #pragma unroll
        for (int g = 0; g < 4; ++g) accB[g] = __builtin_amdgcn_mfma_f32_16x16x32_bf16(AhH[g], hh, accB[g], 0, 0, 0);
        #pragma unroll
        for (int g = 0; g < 4; ++g) accA[g] = __builtin_amdgcn_mfma_f32_16x16x32_bf16(AiH[g], xh, accA[g], 0, 0, 0);
        #pragma unroll
        for (int g = 0; g < 4; ++g) accB[g] = __builtin_amdgcn_mfma_f32_16x16x32_bf16(AhL[g], hh, accB[g], 0, 0, 0);
        #pragma unroll
        for (int g = 0; g < 4; ++g) accA[g] = __builtin_amdgcn_mfma_f32_16x16x32_bf16(AiL[g], xh, accA[g], 0, 0, 0);
        #pragma unroll
        for (int g = 0; g < 4; ++g) accB[g] = __builtin_amdgcn_mfma_f32_16x16x32_bf16(AhH[g], hl, accB[g], 0, 0, 0);
        #pragma unroll
        for (int g = 0; g < 4; ++g) accA[g] = __builtin_amdgcn_mfma_f32_16x16x32_bf16(AiH[g], xl, accA[g], 0, 0, 0);

        // xg(t+1) — h-independent; wave w computes its 4 owned units only
        // (VALU overlaps the MFMA pipe while acc results are in flight)
        {
            float2 uu = ubuf[l15][t + 1];   // t=127 reads pad col; value never consumed
            short hi[4], lo[4];
            #pragma unroll
            for (int r = 0; r < 4; ++r) {
                float g = fmaxf(fmaf(uu.x, wg0[r], fmaf(uu.y, wg1[r], gbc[r])), 0.f);
                fsplit(g, hi[r], lo[r]);
            }
            *(short4v*)&xgh[p ^ 1][l15][16 * w + 4 * q] = (short4v){hi[0], hi[1], hi[2], hi[3]};
            *(short4v*)&xgl[p ^ 1][l15][16 * w + 4 * q] = (short4v){lo[0], lo[1], lo[2], lo[3]};
        }

        // activations + cell update for own units 8q+4w+r
        {
            short hi[4], lo[4];
            #pragma unroll
            for (int r = 0; r < 4; ++r) {
                const float ai = accA[0][r] + accB[0][r];
                const float af = accA[1][r] + accB[1][r];
                const float ag = accA[2][r] + accB[2][r];
                const float ao = accA[3][r] + accB[3][r];
                const float ig = sigm_f(ai);
                const float fg = sigm_f(af);
                const float gg = tanh_f(ag);
                const float og = sigm_f(ao);
                c[r] = fmaf(fg, c[r], ig * gg);
                const float hv = og * tanh_f(c[r]);
                ho[r] = hv;
                fsplit(hv, hi[r], lo[r]);
            }
            *(short4v*)&hhb[p ^ 1][l15][8 * q + 4 * w] = (short4v){hi[0], hi[1], hi[2], hi[3]};
            *(short4v*)&hlb[p ^ 1][l15][8 * q + 4 * w] = (short4v){lo[0], lo[1], lo[2], lo[3]};
        }

        __syncthreads();
        p ^= 1;
    }

    // ---- FC epilogue ----
    float partial = fmaf(ho[0], fcw[0], fmaf(ho[1], fcw[1],
                    fmaf(ho[2], fcw[2], ho[3] * fcw[3])));
    partial += __shfl_xor(partial, 16);
    partial += __shfl_xor(partial, 32);
    if (lane < 16) fcp[w][l15] = partial;
    __syncthreads();
    if (w == 0 && lane < 16) {
        const int node = base + l15;
        if (node < N) out[node] = fcp[0][l15] + fcp[1][l15] + fc_b[0];
    }
}

extern "C" void kernel_launch(void* const* d_in, const int* in_sizes, int n_in,
                              void* d_out, int out_size, void* d_ws, size_t ws_size,
                              hipStream_t stream) {
    const float* x     = (const float*)d_in[0];
    const int*   idx   = (const int*)d_in[1];
    const float* gcn_W = (const float*)d_in[2];
    const float* gcn_b = (const float*)d_in[3];
    const float* w_ih  = (const float*)d_in[4];
    const float* w_hh  = (const float*)d_in[5];
    const float* b_ih  = (const float*)d_in[6];
    const float* b_hh  = (const float*)d_in[7];
    const float* fc_W  = (const float*)d_in[8];
    const float* fc_b  = (const float*)d_in[9];

    const int num_nodes = in_sizes[0] / (SEQ * 2);
    const int ntot = num_nodes * SEQ;
    const int E = in_sizes[1] / 2;

    float* dinv = (float*)d_ws;
    float* agg2 = dinv + ntot;
    float* xs2  = agg2 + 2 * (size_t)ntot;
    const bool packed = ws_size >= (size_t)ntot * sizeof(float) * 5;

    hipMemsetAsync(d_ws, 0, (size_t)ntot * sizeof(float) * 3, stream);

    const int eb = (E + 1023) / 1024;  // 4 edges/thread, 256 threads/block
    count_kernel<<<eb, 256, 0, stream>>>(idx, E, (int*)dinv);
    if (packed) {
        dinv_xs_kernel<<<(ntot + 255) / 256, 256, 0, stream>>>(
            dinv, (const float2*)x, (float2*)xs2, ntot);
        scatter_xs_kernel<<<eb, 256, 0, stream>>>(idx, E, (const float2*)xs2, agg2);
    } else {
        dinv_kernel<<<(ntot + 255) / 256, 256, 0, stream>>>(dinv, ntot);
        scatter_kernel<<<(E + 255) / 256, 256, 0, stream>>>(
            idx, E, (const float2*)x, dinv, agg2);
    }
    lstm_mfma3_kernel<<<(num_nodes + 15) / 16, TPB, 0, stream>>>(
        (const float2*)x, dinv, (const float2*)agg2, num_nodes,
        gcn_W, gcn_b, w_ih, w_hh, b_ih, b_hh, fc_W, fc_b,
        (float*)d_out);
}

// Round 3
// 476.199 us; speedup vs baseline: 1.2701x; 1.2701x over previous
//
#include <hip/hip_runtime.h>

#define SEQ 128
#define HID 32
#define TPB 128   // 2 waves, 16 nodes per block
#define XS 56     // LDS row stride in shorts: 112B = 7*16B -> 2-way-max bank pattern

typedef __attribute__((ext_vector_type(8))) short short8;   // 8 bf16 = 4 VGPR
typedef __attribute__((ext_vector_type(4))) short short4v;  // 4 shorts = 8B
typedef __attribute__((ext_vector_type(4))) float floatx4;  // MFMA acc

// ---------------- GCN prep ----------------

__global__ void count_kernel(const int* __restrict__ idx, int E, int* __restrict__ cnt) {
    int e = (blockIdx.x * blockDim.x + threadIdx.x) * 4;
    if (((E & 3) == 0) && e + 3 < E) {
        int4 d = *(const int4*)(idx + E + e);   // 16B aligned: E%4==0, e%4==0
        atomicAdd(&cnt[d.x], 1);
        atomicAdd(&cnt[d.y], 1);
        atomicAdd(&cnt[d.z], 1);
        atomicAdd(&cnt[d.w], 1);
    } else {
        int lim = min(e + 4, E);
        for (int k = e; k < lim; ++k) atomicAdd(&cnt[idx[E + k]], 1);
    }
}

// packed path: deg is a real int plane; dinv separate; xs = x * dinv pre-scaled.
__global__ void dinv_xs_pk_kernel(const int* __restrict__ deg, float* __restrict__ dinv,
                                  const float2* __restrict__ x2, float2* __restrict__ xs2,
                                  int n) {
    int i = blockIdx.x * blockDim.x + threadIdx.x;
    if (i < n) {
        float dv = rsqrtf((float)deg[i] + 1.0f);
        dinv[i] = dv;
        float2 xx = x2[i];
        xs2[i] = make_float2(xx.x * dv, xx.y * dv);
    }
}

__global__ void dinv_kernel(float* __restrict__ buf, int n) {  // fallback (small ws)
    int i = blockIdx.x * blockDim.x + threadIdx.x;
    if (i < n) buf[i] = rsqrtf((float)__float_as_int(buf[i]) + 1.0f);
}

// Fixed-point pack: q = rn(v * 2^21), biased +2^26 per 32b field. Every added term
// is positive and < 2^26.2 -> no carry between fields up to ~56 adds (max realistic
// deg ~12 for Poisson(0.78)). ONE u64 atomic per edge (native global_atomic_add_x2)
// instead of two f32 atomics: halves the atomic-transaction count scatter is bound by.
__device__ __forceinline__ unsigned long long pk2(float2 v) {
    int qx = __float2int_rn(v.x * 2097152.0f);
    int qy = __float2int_rn(v.y * 2097152.0f);
    return ((unsigned long long)(unsigned)(qx + (1 << 26)) << 32) |
           (unsigned)(qy + (1 << 26));
}

__global__ void scatter_pk_kernel(const int* __restrict__ idx, int E,
                                  const float2* __restrict__ xs2,
                                  unsigned long long* __restrict__ aggP) {
    int e = (blockIdx.x * blockDim.x + threadIdx.x) * 4;
    if (((E & 3) == 0) && e + 3 < E) {
        int4 s = *(const int4*)(idx + e);
        int4 d = *(const int4*)(idx + E + e);
        float2 v0 = xs2[s.x];
        float2 v1 = xs2[s.y];
        float2 v2 = xs2[s.z];
        float2 v3 = xs2[s.w];
        atomicAdd(&aggP[d.x], pk2(v0));
        atomicAdd(&aggP[d.y], pk2(v1));
        atomicAdd(&aggP[d.z], pk2(v2));
        atomicAdd(&aggP[d.w], pk2(v3));
    } else {
        int lim = min(e + 4, E);
        for (int k = e; k < lim; ++k) {
            int s = idx[k];
            int d = idx[E + k];
            atomicAdd(&aggP[d], pk2(xs2[s]));
        }
    }
}

// fallback scatter (workspace too small): float atomics, gather x2 + dinv per edge
__global__ void scatter_kernel(const int* __restrict__ idx, int E,
                               const float2* __restrict__ x2,
                               const float* __restrict__ dinv,
                               float* __restrict__ agg2) {
    int e = blockIdx.x * blockDim.x + threadIdx.x;
    if (e < E) {
        int s = idx[e];
        int d = idx[E + e];
        float ns = dinv[s];
        float2 xs = x2[s];
        unsafeAtomicAdd(&agg2[2 * d + 0], xs.x * ns);
        unsafeAtomicAdd(&agg2[2 * d + 1], xs.y * ns);
    }
}

// ---------------- MFMA LSTM, 2 waves / 16 nodes, low-glue ----------------
// Wave w owns gates i,f,g,o for units 8q+4w+r (row-permuted W tiles; layout
// HW-verified). h and xg cross the wave boundary through LDS rows of SEPARATED
// hi/lo shorts (stride 112B): one ds_read_b128 at [l15*112 + 16q] IS the lane's
// short8 B-frag -> zero unpack VALU. t-loop unrolled x2 with COMPILE-TIME buffer
// parity: all LDS addresses are loop-invariant (no per-step p-select VALU).
// biasC folded into the first MFMA's C-input (D != C) -> no acc-init movs.
// Single barrier per step: epoch reads buf P, writes buf P^1.

__device__ __forceinline__ float sigm_f(float x) {
    return __builtin_amdgcn_rcpf(1.0f + __expf(-x));
}
__device__ __forceinline__ float tanh_f(float x) {
    return fmaf(__builtin_amdgcn_rcpf(1.0f + __expf(-2.0f * x)), 2.0f, -1.0f);
}
// truncation split: f = hi + lo (~2^-16 rel); 3-term MFMA keeps fp32-like precision
__device__ __forceinline__ void fsplit(float f, short& hi, short& lo) {
    unsigned u = __float_as_uint(f);
    hi = (short)(u >> 16);
    float r = f - __uint_as_float(u & 0xFFFF0000u);
    lo = (short)(__float_as_uint(r) >> 16);
}

__global__ __launch_bounds__(TPB, 2) void lstm_mfma3_kernel(
    const float2* __restrict__ x2, const float* __restrict__ dinv,
    const float2* __restrict__ agg2,
    const unsigned long long* __restrict__ aggP, const int* __restrict__ deg,
    int packed, int N,
    const float* __restrict__ gcn_W, const float* __restrict__ gcn_b,
    const float* __restrict__ w_ih, const float* __restrict__ w_hh,
    const float* __restrict__ b_ih, const float* __restrict__ b_hh,
    const float* __restrict__ fc_W, const float* __restrict__ fc_b,
    float* __restrict__ out) {
    __shared__ float2 ubuf[16][SEQ + 1];                 // 16.5 KB (col 128 = scratch)
    __shared__ __align__(16) short xgh[2][16][XS];       // xg hi, row=32 units + pad
    __shared__ __align__(16) short xgl[2][16][XS];       // xg lo
    __shared__ __align__(16) short hhb[2][16][XS];       // h hi
    __shared__ __align__(16) short hlb[2][16][XS];       // h lo
    __shared__ float fcp[2][16];

    const int tid = threadIdx.x;
    const int w = tid >> 6;       // wave id = mtl
    const int lane = tid & 63;
    const int l15 = lane & 15;
    const int q = lane >> 4;
    const int base = blockIdx.x * 16;

    // ---- Phase A: stage u[node][t] = dv*(agg + x*dv) into LDS (coalesced) ----
    {
        const float2* xb  = x2   + (size_t)base * SEQ;
        const float*  db  = dinv + (size_t)base * SEQ;
        const float2* agb = agg2 + (size_t)base * SEQ;
        const unsigned long long* apb = aggP + (size_t)base * SEQ;
        const int* dgb = deg + (size_t)base * SEQ;
        const int lim = min(16 * SEQ, (N - base) * SEQ);
        for (int i = tid; i < 16 * SEQ; i += TPB) {
            float2 v = make_float2(0.f, 0.f);
            if (i < lim) {
                float dv = db[i];
                float2 xx = xb[i];
                float ax, ay;
                if (packed) {
                    unsigned long long pk = apb[i];
                    unsigned bias = (unsigned)dgb[i] * 67108864u;  // deg * 2^26
                    ax = (float)((int)((unsigned)(pk >> 32) - bias)) * (1.0f / 2097152.0f);
                    ay = (float)((int)((unsigned)pk - bias)) * (1.0f / 2097152.0f);
                } else {
                    float2 a = agb[i];
                    ax = a.x; ay = a.y;
                }
                v = make_float2(dv * fmaf(xx.x, dv, ax), dv * fmaf(xx.y, dv, ay));
            }
            ubuf[i >> 7][i & 127] = v;
        }
    }

    // ---- constant A-frags (4 tiles = gates i,f,g,o at mtl=w), hi/lo bf16 ----
    short8 AiH[4], AiL[4], AhH[4], AhL[4];
    floatx4 biasC[4];
    #pragma unroll
    for (int g = 0; g < 4; ++g) {
        const int arow = g * 32 + 8 * (l15 >> 2) + 4 * w + (l15 & 3);
        const float* wi = w_ih + arow * HID + 8 * q;
        const float* wh = w_hh + arow * HID + 8 * q;
        #pragma unroll
        for (int j = 0; j < 8; ++j) {
            short h16, l16;
            fsplit(wi[j], h16, l16); AiH[g][j] = h16; AiL[g][j] = l16;
            fsplit(wh[j], h16, l16); AhH[g][j] = h16; AhL[g][j] = l16;
        }
        #pragma unroll
        for (int r = 0; r < 4; ++r) {
            const int brow = g * 32 + 8 * q + 4 * w + r;
            biasC[g][r] = b_ih[brow] + b_hh[brow];
        }
    }

    // ---- GCN consts for xg units owned by THIS lane: u = 16w + 4q + r ----
    float wg0[4], wg1[4], gbc[4], fcw[4];
    #pragma unroll
    for (int r = 0; r < 4; ++r) {
        const int u = 16 * w + 4 * q + r;
        wg0[r] = gcn_W[u];
        wg1[r] = gcn_W[HID + u];
        gbc[r] = gcn_b[u];
        fcw[r] = fc_W[8 * q + 4 * w + r];   // FC consts for own C-slots
    }

    float c[4] = {0.f, 0.f, 0.f, 0.f};
    float ho[4] = {0.f, 0.f, 0.f, 0.f};

    __syncthreads();  // ubuf staged

    // ---- prologue: xg(0) and h(-1)=0 into buffer 0 ----
    {
        float2 uu = ubuf[l15][0];
        short hi[4], lo[4];
        #pragma unroll
        for (int r = 0; r < 4; ++r) {
            float g = fmaxf(fmaf(uu.x, wg0[r], fmaf(uu.y, wg1[r], gbc[r])), 0.f);
            fsplit(g, hi[r], lo[r]);
        }
        *(short4v*)&xgh[0][l15][16 * w + 4 * q] = (short4v){hi[0], hi[1], hi[2], hi[3]};
        *(short4v*)&xgl[0][l15][16 * w + 4 * q] = (short4v){lo[0], lo[1], lo[2], lo[3]};
        *(short4v*)&hhb[0][l15][8 * q + 4 * w] = (short4v){0, 0, 0, 0};
        *(short4v*)&hlb[0][l15][8 * q + 4 * w] = (short4v){0, 0, 0, 0};
    }
    __syncthreads();

// One time-step with compile-time buffer parity P (reads buf P, writes buf P^1).
// Term-major MFMA: 4 independent chains (gates), depth 6, bias folded into C-in.
#define LSTM_STEP(P, TT)                                                                   \
    do {                                                                                   \
        const short8 xh = *(const short8*)&xgh[P][l15][8 * q];                             \
        const short8 xl = *(const short8*)&xgl[P][l15][8 * q];                             \
        const short8 hh = *(const short8*)&hhb[P][l15][8 * q];                             \
        const short8 hl = *(const short8*)&hlb[P][l15][8 * q];                             \
        floatx4 acc[4];                                                                    \
        __builtin_amdgcn_s_setprio(1);                                                     \
        _Pragma("unroll") for (int g = 0; g < 4; ++g)                                      \
            acc[g] = __builtin_amdgcn_mfma_f32_16x16x32_bf16(AiH[g], xh, biasC[g], 0, 0, 0); \
        _Pragma("unroll") for (int g = 0; g < 4; ++g)                                      \
            acc[g] = __builtin_amdgcn_mfma_f32_16x16x32_bf16(AiL[g], xh, acc[g], 0, 0, 0); \
        _Pragma("unroll") for (int g = 0; g < 4; ++g)                                      \
            acc[g] = __builtin_amdgcn_mfma_f32_16x16x32_bf16(AiH[g], xl, acc[g], 0, 0, 0); \
        _Pragma("unroll") for (int g = 0; g < 4; ++g)                                      \
            acc[g] = __builtin_amdgcn_mfma_f32_16x16x32_bf16(AhH[g], hh, acc[g], 0, 0, 0); \
        _Pragma("unroll") for (int g = 0; g < 4; ++g)                                      \
            acc[g] = __builtin_amdgcn_mfma_f32_16x16x32_bf16(AhL[g], hh, acc[g], 0, 0, 0); \
        _Pragma("unroll") for (int g = 0; g < 4; ++g)                                      \
            acc[g] = __builtin_amdgcn_mfma_f32_16x16x32_bf16(AhH[g], hl, acc[g], 0, 0, 0); \
        __builtin_amdgcn_s_setprio(0);                                                     \
        {                                                                                  \
            float2 uu = ubuf[l15][(TT) + 1]; /* last step reads pad col; unused */         \
            short hi[4], lo[4];                                                            \
            _Pragma("unroll") for (int r = 0; r < 4; ++r) {                                \
                float g = fmaxf(fmaf(uu.x, wg0[r], fmaf(uu.y, wg1[r], gbc[r])), 0.f);      \
                fsplit(g, hi[r], lo[r]);                                                   \
            }                                                                              \
            *(short4v*)&xgh[(P) ^ 1][l15][16 * w + 4 * q] =                                \
                (short4v){hi[0], hi[1], hi[2], hi[3]};                                     \
            *(short4v*)&xgl[(P) ^ 1][l15][16 * w + 4 * q] =                                \
                (short4v){lo[0], lo[1], lo[2], lo[3]};                                     \
        }                                                                                  \
        {                                                                                  \
            short hi[4], lo[4];                                                            \
            _Pragma("unroll") for (int r = 0; r < 4; ++r) {                                \
                const float ig = sigm_f(acc[0][r]);                                        \
                const float fg = sigm_f(acc[1][r]);                                        \
                const float gg = tanh_f(acc[2][r]);                                        \
                const float og = sigm_f(acc[3][r]);                                        \
                c[r] = fmaf(fg, c[r], ig * gg);                                            \
                const float hv = og * tanh_f(c[r]);                                        \
                ho[r] = hv;                                                                \
                fsplit(hv, hi[r], lo[r]);                                                  \
            }                                                                              \
            *(short4v*)&hhb[(P) ^ 1][l15][8 * q + 4 * w] =                                 \
                (short4v){hi[0], hi[1], hi[2], hi[3]};                                     \
            *(short4v*)&hlb[(P) ^ 1][l15][8 * q + 4 * w] =                                 \
                (short4v){lo[0], lo[1], lo[2], lo[3]};                                     \
        }                                                                                  \
        __syncthreads();                                                                   \
    } while (0)

    #pragma unroll 1
    for (int t = 0; t < SEQ; t += 2) {
        LSTM_STEP(0, t);        // reads buf 0 (xg(t), h(t-1)), writes buf 1
        LSTM_STEP(1, t + 1);    // reads buf 1, writes buf 0
    }
#undef LSTM_STEP

    // ---- FC epilogue ----
    float partial = fmaf(ho[0], fcw[0], fmaf(ho[1], fcw[1],
                    fmaf(ho[2], fcw[2], ho[3] * fcw[3])));
    partial += __shfl_xor(partial, 16);
    partial += __shfl_xor(partial, 32);
    if (lane < 16) fcp[w][l15] = partial;
    __syncthreads();
    if (w == 0 && lane < 16) {
        const int node = base + l15;
        if (node < N) out[node] = fcp[0][l15] + fcp[1][l15] + fc_b[0];
    }
}

extern "C" void kernel_launch(void* const* d_in, const int* in_sizes, int n_in,
                              void* d_out, int out_size, void* d_ws, size_t ws_size,
                              hipStream_t stream) {
    const float* x     = (const float*)d_in[0];
    const int*   idx   = (const int*)d_in[1];
    const float* gcn_W = (const float*)d_in[2];
    const float* gcn_b = (const float*)d_in[3];
    const float* w_ih  = (const float*)d_in[4];
    const float* w_hh  = (const float*)d_in[5];
    const float* b_ih  = (const float*)d_in[6];
    const float* b_hh  = (const float*)d_in[7];
    const float* fc_W  = (const float*)d_in[8];
    const float* fc_b  = (const float*)d_in[9];

    const int num_nodes = in_sizes[0] / (SEQ * 2);
    const int ntot = num_nodes * SEQ;
    const int E = in_sizes[1] / 2;

    // packed layout: dinv[ntot f32] | deg[ntot i32] | aggP[ntot u64] | xs2[ntot f32x2]
    float* dinv = (float*)d_ws;
    int* deg = (int*)d_ws + ntot;
    unsigned long long* aggP = (unsigned long long*)((float*)d_ws + 2 * (size_t)ntot);
    float* xs2 = (float*)d_ws + 4 * (size_t)ntot;
    const bool packed = ws_size >= (size_t)ntot * sizeof(float) * 6;

    const int eb = (E + 1023) / 1024;  // 4 edges/thread, 256 threads/block
    if (packed) {
        hipMemsetAsync(deg, 0, (size_t)ntot * sizeof(float) * 3, stream);  // deg + aggP
        count_kernel<<<eb, 256, 0, stream>>>(idx, E, deg);
        dinv_xs_pk_kernel<<<(ntot + 255) / 256, 256, 0, stream>>>(
            deg, dinv, (const float2*)x, (float2*)xs2, ntot);
        scatter_pk_kernel<<<eb, 256, 0, stream>>>(idx, E, (const float2*)xs2, aggP);
        lstm_mfma3_kernel<<<(num_nodes + 15) / 16, TPB, 0, stream>>>(
            (const float2*)x, dinv, (const float2*)xs2 /*unused*/, aggP, deg, 1, num_nodes,
            gcn_W, gcn_b, w_ih, w_hh, b_ih, b_hh, fc_W, fc_b, (float*)d_out);
    } else {
        // fallback: dinv[ntot] | agg2[2*ntot] float atomics
        float* agg2 = (float*)d_ws + ntot;
        hipMemsetAsync(d_ws, 0, (size_t)ntot * sizeof(float) * 3, stream);
        count_kernel<<<eb, 256, 0, stream>>>(idx, E, (int*)dinv);
        dinv_kernel<<<(ntot + 255) / 256, 256, 0, stream>>>(dinv, ntot);
        scatter_kernel<<<(E + 255) / 256, 256, 0, stream>>>(
            idx, E, (const float2*)x, dinv, agg2);
        lstm_mfma3_kernel<<<(num_nodes + 15) / 16, TPB, 0, stream>>>(
            (const float2*)x, dinv, (const float2*)agg2,
            (const unsigned long long*)agg2 /*unused*/, (const int*)dinv /*unused*/,
            0, num_nodes,
            gcn_W, gcn_b, w_ih, w_hh, b_ih, b_hh, fc_W, fc_b, (float*)d_out);
    }
}